// Round 6
// baseline (432.480 us; speedup 1.0000x reference)
//
#include <hip/hip_runtime.h>

// Batched ADMM QP solver. One block (256 thr, 4 waves) per batch; grid 1024 ->
// exactly 4 blocks/CU resident (LDS 36.2 KB), 4 waves/SIMD.
// Setup: K = AtA + Q + sigma*I at (row i, 16-col chunk qc) per thread; register
//   Gauss-Jordan (SPD, no pivoting); c = Kinv*p via quad-DPP (Kinv stays in regs);
//   d = -A*c; M = Kinv*At built in two 32-row passes into LDS; P = A*M fragments
//   pacc[3][10] per lane (8-lane group g owns rows 3g..3g+2, lane cc cols 10cc..+9).
// Iterate 799x: s = P*w + d + y; z = clip(s,l,u); y = s-z; w = z-y  (1 barrier/iter,
//   8-lane DPP reduction, w double-buffered in padded 12-float rows).
// Epilogue: x = Kinv*(At*w) - c  (Kinv from registers, c from register).

#define ITERS 800
#define SIGMA 1e-6f
#define WAM  68     // amat row stride
#define MROW 96     // M half-buffer row stride (8 chunks of 12)
#define WROW 12     // padded w chunk stride (10 used + 2 pad)

// x + dpp_perm(x): 0xB1 quad xor1, 0x4E quad xor2, 0x141 row_half_mirror (xor
// across the two quads of an 8-lane group). All VALU-pipe.
__device__ __forceinline__ float dpp_add(float x, const int ctrl) {
    int yi;
    switch (ctrl) {
        case 0xB1:  yi = __builtin_amdgcn_update_dpp(0, __float_as_int(x), 0xB1,  0xF, 0xF, true); break;
        case 0x4E:  yi = __builtin_amdgcn_update_dpp(0, __float_as_int(x), 0x4E,  0xF, 0xF, true); break;
        default:    yi = __builtin_amdgcn_update_dpp(0, __float_as_int(x), 0x141, 0xF, 0xF, true); break;
    }
    return x + __int_as_float(yi);
}

__global__ __launch_bounds__(256, 4)
void admm_qp_kernel(const float* __restrict__ Q, const float* __restrict__ p,
                    const float* __restrict__ A, const float* __restrict__ bvec,
                    const float* __restrict__ G, const float* __restrict__ h,
                    float* __restrict__ out)
{
    __shared__ float amat[80 * WAM];                  // 5440
    __shared__ float mh[32 * MROW];                   // 3072 (M rows 32ps..32ps+31)
    __shared__ float fcol[64];
    __shared__ float prow[64];
    __shared__ float pvec[64];
    __shared__ float cvec[64];
    __shared__ float dvec[80];
    __shared__ __align__(16) float wbuf[2 * 8 * WROW];

    const int b  = blockIdx.x;
    const int t  = threadIdx.x;
    const int i  = t >> 2, qc = t & 3;   // setup/epilogue mapping (row, 16-col chunk)
    const int g  = t >> 3, cc = t & 7;   // P/iteration mapping (3-row group, 10-col lane)

    const float* Ab = A + (size_t)b * 16 * 64;
    const float* Gb = G + (size_t)b * 64 * 64;
    const float* Qb = Q + (size_t)b * 64 * 64;

    // ---- stage Amat=[A;G], pvec; zero w buffers ----
    for (int e = t; e < 80 * 16; e += 256) {
        int row = e >> 4, seg = e & 15;
        const float* src = (row < 16) ? (Ab + row * 64 + seg * 4)
                                      : (Gb + (row - 16) * 64 + seg * 4);
        *(float4*)&amat[row * WAM + seg * 4] = *(const float4*)src;
    }
    if (t < 64) pvec[t] = p[(size_t)b * 64 + t];
    if (t < 2 * 8 * WROW) wbuf[t] = 0.f;
    __syncthreads();

    // ---- K = AtA + Q + sigma*I: thread (i,qc) owns row i, cols 16qc..+15 ----
    float ar[16];
#pragma unroll
    for (int c = 0; c < 16; ++c) ar[c] = 0.f;
    for (int k = 0; k < 80; ++k) {
        const float* rowk = &amat[k * WAM];
        float av = rowk[i];
#pragma unroll
        for (int c4 = 0; c4 < 4; ++c4) {
            float4 bv = *(const float4*)&rowk[qc * 16 + 4 * c4];
            ar[4*c4+0] += av * bv.x; ar[4*c4+1] += av * bv.y;
            ar[4*c4+2] += av * bv.z; ar[4*c4+3] += av * bv.w;
        }
    }
#pragma unroll
    for (int c4 = 0; c4 < 4; ++c4) {
        float4 qv = *(const float4*)&Qb[i * 64 + qc * 16 + 4 * c4];
        ar[4*c4+0] += qv.x; ar[4*c4+1] += qv.y; ar[4*c4+2] += qv.z; ar[4*c4+3] += qv.w;
    }
    if ((i >> 4) == qc) ar[i & 15] += SIGMA;

    // ---- register Gauss-Jordan, in place (K SPD, no pivoting) ----
    for (int po = 0; po < 4; ++po) {
#pragma unroll
        for (int pi = 0; pi < 16; ++pi) {
            const int pv = po * 16 + pi;
            if (qc == po) fcol[i] = ar[pi];
            __syncthreads();
            float pr = 1.0f / fcol[pv];
            float f  = fcol[i];
            if (i == pv) {
                float sp[16];
#pragma unroll
                for (int c = 0; c < 16; ++c) sp[c] = ar[c] * pr;
                if (qc == po) sp[pi] = pr;
#pragma unroll
                for (int c4 = 0; c4 < 4; ++c4)
                    *(float4*)&prow[qc * 16 + 4 * c4] =
                        make_float4(sp[4*c4], sp[4*c4+1], sp[4*c4+2], sp[4*c4+3]);
            }
            __syncthreads();
            float sp[16];
#pragma unroll
            for (int c4 = 0; c4 < 4; ++c4) {
                float4 v = *(const float4*)&prow[qc * 16 + 4 * c4];
                sp[4*c4] = v.x; sp[4*c4+1] = v.y; sp[4*c4+2] = v.z; sp[4*c4+3] = v.w;
            }
            if (i == pv) {
#pragma unroll
                for (int c = 0; c < 16; ++c) ar[c] = sp[c];
            } else {
#pragma unroll
                for (int c = 0; c < 16; ++c) ar[c] -= f * sp[c];
                if (qc == po) ar[pi] = -f * pr;
            }
        }
    }

    // ---- c = Kinv*p (quad-DPP reduce, Kinv stays in ar) ----
    float creg;
    {
        float cacc = 0.f;
#pragma unroll
        for (int c4 = 0; c4 < 4; ++c4) {
            float4 pv4 = *(const float4*)&pvec[qc * 16 + 4 * c4];
            cacc += ar[4*c4]*pv4.x + ar[4*c4+1]*pv4.y + ar[4*c4+2]*pv4.z + ar[4*c4+3]*pv4.w;
        }
        cacc = dpp_add(cacc, 0xB1);
        cacc = dpp_add(cacc, 0x4E);
        creg = cacc;
        if (qc == 0) cvec[i] = cacc;
    }
    __syncthreads();

    // ---- d = -A*c ----
    if (t < 80) {
        float acc = 0.f;
#pragma unroll
        for (int k4 = 0; k4 < 16; ++k4) {
            float4 avv = *(const float4*)&amat[t * WAM + 4 * k4];
            float4 cv4 = *(const float4*)&cvec[4 * k4];
            acc += avv.x*cv4.x + avv.y*cv4.y + avv.z*cv4.z + avv.w*cv4.w;
        }
        dvec[t] = -acc;
    }
    __syncthreads();

    // ---- per-lane row state (group g owns rows 3g..3g+2; dummies clamp to 79) ----
    int rr[3];
    float dR[3], lR[3], uR[3], dyR[3];
#pragma unroll
    for (int j = 0; j < 3; ++j) {
        int r = 3 * g + j; if (r > 79) r = 79;
        rr[j] = r;
        dR[j] = dvec[r];
        if (r < 16) { float bb = bvec[(size_t)b * 16 + r]; lR[j] = bb; uR[j] = bb; }
        else        { lR[j] = -1e8f; uR[j] = h[(size_t)b * 64 + (r - 16)]; }
        dyR[j] = dR[j];          // y0 = 0
    }

    // ---- P = A*(Kinv*At): two k-passes; M rows 32ps..+31 in mh ----
    float pacc[3][10];
#pragma unroll
    for (int j = 0; j < 3; ++j)
#pragma unroll
        for (int c = 0; c < 10; ++c) pacc[j][c] = 0.f;

    for (int ps = 0; ps < 2; ++ps) {
        if ((t >> 7) == ps) {                 // waves 0,1 build rows 0..31; 2,3 rows 32..63
            const int mrow = i & 31;
            for (int jo = 0; jo < 8; ++jo) {
#pragma unroll
                for (int ji = 0; ji < 10; ++ji) {
                    const int j = jo * 10 + ji;
                    const float* rj = &amat[j * WAM + qc * 16];
                    float acc = 0.f;
#pragma unroll
                    for (int c4 = 0; c4 < 4; ++c4) {
                        float4 av = *(const float4*)&rj[4 * c4];
                        acc += ar[4*c4]*av.x + ar[4*c4+1]*av.y + ar[4*c4+2]*av.z + ar[4*c4+3]*av.w;
                    }
                    acc = dpp_add(acc, 0xB1);
                    acc = dpp_add(acc, 0x4E);
                    if (qc == (ji & 3)) mh[mrow * MROW + jo * WROW + ji] = acc;
                }
            }
        }
        __syncthreads();
#pragma unroll 2
        for (int kb = 0; kb < 8; ++kb) {
            float a0[4], a1[4], a2[4];
            { float4 v = *(const float4*)&amat[rr[0]*WAM + ps*32 + kb*4]; a0[0]=v.x;a0[1]=v.y;a0[2]=v.z;a0[3]=v.w; }
            { float4 v = *(const float4*)&amat[rr[1]*WAM + ps*32 + kb*4]; a1[0]=v.x;a1[1]=v.y;a1[2]=v.z;a1[3]=v.w; }
            { float4 v = *(const float4*)&amat[rr[2]*WAM + ps*32 + kb*4]; a2[0]=v.x;a2[1]=v.y;a2[2]=v.z;a2[3]=v.w; }
#pragma unroll
            for (int kk = 0; kk < 4; ++kk) {
                const float* mrp = &mh[(kb * 4 + kk) * MROW + cc * WROW];
                float4 ma = *(const float4*)&mrp[0];
                float4 mb = *(const float4*)&mrp[4];
                float2 mc = *(const float2*)&mrp[8];
                float m[10] = {ma.x, ma.y, ma.z, ma.w, mb.x, mb.y, mb.z, mb.w, mc.x, mc.y};
#pragma unroll
                for (int c = 0; c < 10; ++c) {
                    pacc[0][c] += a0[kk] * m[c];
                    pacc[1][c] += a1[kk] * m[c];
                    pacc[2][c] += a2[kk] * m[c];
                }
            }
        }
        __syncthreads();
    }

    // ---- 799 iterations: s = P*w + d + y; z = clip; y = s-z; w = z-y ----
    const int wrow  = 3 * g + cc;
    const bool wvalid = (cc < 3) && (wrow < 80);
    const int widx  = (wrow < 80) ? ((wrow / 10) * WROW + (wrow % 10)) : 0;

#define DOT10(acc, row) \
    acc = pacc[row][0]*v04.x + pacc[row][1]*v04.y + pacc[row][2]*v04.z + pacc[row][3]*v04.w \
        + pacc[row][4]*v47.x + pacc[row][5]*v47.y + pacc[row][6]*v47.z + pacc[row][7]*v47.w \
        + pacc[row][8]*v89.x + pacc[row][9]*v89.y;
#define RED8(a) a = dpp_add(a, 0xB1); a = dpp_add(a, 0x4E); a = dpp_add(a, 0x141);
#define UPD(j, aj, wj) \
    { float s = aj + dyR[j]; float z = fminf(fmaxf(s, lR[j]), uR[j]); \
      float yn = s - z; dyR[j] = dR[j] + yn; wj = z - yn; }

    float* wc = wbuf;
    float* wn = wbuf + 8 * WROW;
    for (int it = 0; it < ITERS - 1; ++it) {
        const float* wp = wc + cc * WROW;
        float4 v04 = *(const float4*)&wp[0];
        float4 v47 = *(const float4*)&wp[4];
        float2 v89 = *(const float2*)&wp[8];
        float a0, a1, a2;
        DOT10(a0, 0) DOT10(a1, 1) DOT10(a2, 2)
        RED8(a0) RED8(a1) RED8(a2)
        float w0, w1, w2;
        UPD(0, a0, w0) UPD(1, a1, w1) UPD(2, a2, w2)
        float wsel = (cc == 1) ? w1 : ((cc == 2) ? w2 : w0);
        if (wvalid) wn[widx] = wsel;
        __syncthreads();
        float* tmp = wc; wc = wn; wn = tmp;
    }

    // ---- epilogue: x = Kinv*(At*w_799) - c ----
    if (t < 64) {
        float acc = 0.f;
        for (int jo = 0; jo < 8; ++jo) {
#pragma unroll
            for (int ji = 0; ji < 10; ++ji)
                acc += amat[(jo * 10 + ji) * WAM + t] * wc[jo * WROW + ji];
        }
        fcol[t] = acc;
    }
    __syncthreads();
    float xp = 0.f;
#pragma unroll
    for (int c4 = 0; c4 < 4; ++c4) {
        float4 fv = *(const float4*)&fcol[qc * 16 + 4 * c4];
        xp += ar[4*c4]*fv.x + ar[4*c4+1]*fv.y + ar[4*c4+2]*fv.z + ar[4*c4+3]*fv.w;
    }
    xp = dpp_add(xp, 0xB1);
    xp = dpp_add(xp, 0x4E);
    if (qc == 0) out[(size_t)b * 64 + i] = xp - creg;
}

extern "C" void kernel_launch(void* const* d_in, const int* in_sizes, int n_in,
                              void* d_out, int out_size, void* d_ws, size_t ws_size,
                              hipStream_t stream) {
    const float* Q    = (const float*)d_in[0];
    const float* p    = (const float*)d_in[1];
    const float* A    = (const float*)d_in[2];
    const float* bvec = (const float*)d_in[3];
    const float* G    = (const float*)d_in[4];
    const float* h    = (const float*)d_in[5];
    float* out = (float*)d_out;
    admm_qp_kernel<<<1024, 256, 0, stream>>>(Q, p, A, bvec, G, h, out);
}